// Round 1
// baseline (948.042 us; speedup 1.0000x reference)
//
#include <hip/hip_runtime.h>
#include <stdint.h>

#define ROW    32768
#define BLOCK  1024
#define V4PT   8          // float4 per thread
#define EPT    32         // elements per thread
#define KSEL   64
#define NCOPY  16         // histogram copies (bank-staggered)

__device__ __forceinline__ float block_reduce_sum(float v, float* scratch, int tid) {
    #pragma unroll
    for (int off = 32; off > 0; off >>= 1)
        v += __shfl_down(v, off, 64);
    int wid = tid >> 6;
    if ((tid & 63) == 0) scratch[wid] = v;
    __syncthreads();
    if (tid < 64) {
        float t = (tid < (BLOCK / 64)) ? scratch[tid] : 0.0f;
        #pragma unroll
        for (int off = 8; off > 0; off >>= 1)
            t += __shfl_down(t, off, 64);
        if (tid == 0) scratch[0] = t;
    }
    __syncthreads();
    float r = scratch[0];
    __syncthreads();
    return r;
}

__device__ __forceinline__ float val_from_key(uint32_t u) {
    uint32_t b = (u & 0x80000000u) ? (u ^ 0x80000000u) : ~u;
    return __uint_as_float(b);
}

extern "C" __global__ __launch_bounds__(BLOCK, 4)
void remax_topk_kernel(const float* __restrict__ x, float* __restrict__ out) {
    const int row = blockIdx.x;
    const int tid = threadIdx.x;
    const float4* __restrict__ xr = (const float4*)(x + (size_t)row * ROW);
    float4* __restrict__ orow = (float4*)(out + (size_t)row * ROW);

    __shared__ uint32_t hist[NCOPY * 257];
    __shared__ uint32_t cnt[256];
    __shared__ uint32_t sel[2];
    __shared__ float    fscratch[20];

    // ---- load row into registers; key-transform; relu partial sum ----
    uint32_t u[EPT];
    float relusum = 0.0f;
    #pragma unroll
    for (int i = 0; i < V4PT; i++) {
        float4 f = xr[i * BLOCK + tid];
        float fc[4] = {f.x, f.y, f.z, f.w};
        #pragma unroll
        for (int c = 0; c < 4; c++) {
            float xf = fc[c];
            relusum += fmaxf(xf, 0.0f);
            uint32_t b = __float_as_uint(xf);
            uint32_t s = (uint32_t)((int32_t)b >> 31);
            u[i * 4 + c] = b ^ (s | 0x80000000u);   // order-preserving key
        }
    }
    float mag = block_reduce_sum(relusum, fscratch, tid);

    // ---- exact 4-pass 8-bit MSD radix select for 64th-largest key ----
    uint32_t pfx = 0, maskHi = 0, rem = KSEL;
    const int copy = tid & (NCOPY - 1);

    for (int pass = 0; pass < 4; pass++) {
        const int shift = 24 - 8 * pass;
        for (int j = tid; j < NCOPY * 257; j += BLOCK) hist[j] = 0;
        __syncthreads();

        #pragma unroll
        for (int i = 0; i < EPT; i++) {
            uint32_t ui = u[i];
            if ((ui & maskHi) == pfx) {
                uint32_t d = (ui >> shift) & 255u;
                atomicAdd(&hist[copy * 257 + d], 1u);
            }
        }
        __syncthreads();

        if (tid < 256) {
            uint32_t s = 0;
            #pragma unroll
            for (int c = 0; c < NCOPY; c++) s += hist[c * 257 + tid];
            cnt[tid] = s;
        }
        __syncthreads();

        if (tid < 64) {
            uint32_t c0 = cnt[4 * tid + 0], c1 = cnt[4 * tid + 1];
            uint32_t c2 = cnt[4 * tid + 2], c3 = cnt[4 * tid + 3];
            uint32_t s3 = c3, s2 = c2 + s3, s1 = c1 + s2, s0 = c0 + s1;
            // wave-wide inclusive suffix sum of s0 across lanes
            uint32_t acc = s0;
            #pragma unroll
            for (int off = 1; off < 64; off <<= 1) {
                uint32_t o = __shfl_down(acc, off, 64);
                acc += (tid + off < 64) ? o : 0u;
            }
            uint32_t above = acc - s0;  // sum over lanes > this lane
            uint32_t suf[5] = {above + s0, above + s1, above + s2, above + s3, above};
            #pragma unroll
            for (int i2 = 0; i2 < 4; i2++) {
                if (suf[i2] >= rem && suf[i2 + 1] < rem) {
                    sel[0] = (uint32_t)(4 * tid + i2);
                    sel[1] = rem - suf[i2 + 1];
                }
            }
        }
        __syncthreads();
        uint32_t d = sel[0];
        rem = sel[1];
        pfx |= d << shift;
        maskHi |= 0xFFu << shift;
        // next pass's writes to sel happen after >=2 barriers; safe
    }

    const uint32_t T = pfx;

    // ---- sum of strictly-greater values; tie adjustment ----
    float sgt = 0.0f;
    #pragma unroll
    for (int i = 0; i < EPT; i++) {
        if (u[i] > T) sgt += val_from_key(u[i]);
    }
    float sum_gt = block_reduce_sum(sgt, fscratch, tid);
    float magk = sum_gt + (float)rem * val_from_key(T);

    float scale = magk / mag;
    if (!__builtin_isfinite(scale)) scale = 0.0f;

    // ---- write out = relu(x) * scale ----
    #pragma unroll
    for (int i = 0; i < V4PT; i++) {
        float4 o;
        float r0 = (u[i * 4 + 0] > 0x80000000u) ? __uint_as_float(u[i * 4 + 0] ^ 0x80000000u) : 0.0f;
        float r1 = (u[i * 4 + 1] > 0x80000000u) ? __uint_as_float(u[i * 4 + 1] ^ 0x80000000u) : 0.0f;
        float r2 = (u[i * 4 + 2] > 0x80000000u) ? __uint_as_float(u[i * 4 + 2] ^ 0x80000000u) : 0.0f;
        float r3 = (u[i * 4 + 3] > 0x80000000u) ? __uint_as_float(u[i * 4 + 3] ^ 0x80000000u) : 0.0f;
        o.x = r0 * scale; o.y = r1 * scale; o.z = r2 * scale; o.w = r3 * scale;
        orow[i * BLOCK + tid] = o;
    }
}

extern "C" void kernel_launch(void* const* d_in, const int* in_sizes, int n_in,
                              void* d_out, int out_size, void* d_ws, size_t ws_size,
                              hipStream_t stream) {
    const float* x = (const float*)d_in[0];
    float* out = (float*)d_out;
    int rows = in_sizes[0] / ROW;
    remax_topk_kernel<<<rows, BLOCK, 0, stream>>>(x, out);
}